// Round 12
// baseline (124.779 us; speedup 1.0000x reference)
//
#include <hip/hip_runtime.h>
#include <stdint.h>

// ShuffledGroupWhitening on MI355X.
// x: [3*8192, 1024] f32, perms: [3,1024] i32.
// Per (view s, group g): gather 16 permuted cols, center over batch,
// whiten with cov^{-1/2} (Newton-Schulz), scatter back (same col set).
//
// R11 -> R12: stats' 58 us invariant = TA address-throughput bound (25.2M
// scattered dword addresses). Fix: transpose x once into bf16 xT[3][1024][8192]
// (coalesced tiled transpose, 150 MB stream), then each thread's 4 random
// columns become CONTIGUOUS 64B runs: 16 addresses/thread instead of 128,
// every line fully consumed. bf16 only affects statistics (self-averaging:
// cov err ~3e-5). Partials + xT coexist in d_out (77 MB < 100.7 MB); apply
// overwrites d_out afterwards. reduce1/invsqrt/apply byte-identical to R11.

constexpr int D_FEAT  = 1024;
constexpr int NGROUP  = 64;
constexpr int GD      = 16;     // group dim
constexpr int NB      = 8192;   // rows per view
constexpr int NVIEW   = 3;

constexpr int P1      = 256;    // stats blocks per view (768 total = 3/CU)
constexpr int RPP1    = NB / P1;        // 32 rows per stats block
constexpr int RPB3    = 32;     // rows per apply block
constexpr int C3      = 4;      // chunk rows (apply)
constexpr int PSPLIT  = 8;      // reduce split factor
constexpr int PER     = P1 / PSPLIT;    // 32 partials per reduce1 block

constexpr int SXX_FLOATS  = NGROUP * GD * GD;        // 16384 per view
constexpr int PART_STRIDE = SXX_FLOATS + D_FEAT;     // 17408 entries per partial
constexpr int PSTRIDE_U32 = PART_STRIDE / 2;         // 8704 dwords (bf16-packed)
constexpr int ENT         = NVIEW * PART_STRIDE;     // 52224 stat entries
constexpr int ENT_DW      = NVIEW * PSTRIDE_U32;     // 26112 packed dwords

// d_out scratch layout (dwords): partials then bf16 xT
constexpr int PART_DW_TOTAL = NVIEW * P1 * PSTRIDE_U32;   // 6,684,672 dw = 26.7 MB
constexpr int XT_OFF_DW     = PART_DW_TOTAL;              // 16B-aligned (div by 4)
// xT: column c of view s = 8192 bf16 = 4096 dw = 1024 uint4; total 50.3 MB

// ws layout (floats)
constexpr int SX_OFF  = 0;                           // [3][1024] raw col sums
constexpr int W_OFF   = SX_OFF + NVIEW * D_FEAT;     // 3072: [3][64][16][16]
constexpr int RED_OFF = W_OFF + NVIEW * SXX_FLOATS;  // 52224: [8][52224] f32
// total ws use = RED_OFF + PSPLIT*ENT = 470016 floats ~ 1.9 MB

// quad broadcast: every lane gets lane ((lane&~3)+B)'s value. Pure VALU DPP.
template <int B>
__device__ __forceinline__ float qbc(float x) {
    return __int_as_float(__builtin_amdgcn_mov_dpp(
        __float_as_int(x), B * 0x55 /*quad_perm[B,B,B,B]*/, 0xF, 0xF, true));
}

// pack two floats to bf16x2 (round-to-nearest-even), a in low half
__device__ __forceinline__ uint32_t pkbf2(float a, float b) {
    uint32_t ua = __float_as_uint(a), ub = __float_as_uint(b);
    ua += 0x7FFFu + ((ua >> 16) & 1u);
    ub += 0x7FFFu + ((ub >> 16) & 1u);
    return (ua >> 16) | (ub & 0xFFFF0000u);
}

// ---------------- Pass 0: x (f32 row-major) -> xT (bf16 col-major) ----------------
// 64x64 tile per block, 256 threads. Coalesced load, LDS[64][65], coalesced
// bf16-packed store (each thread owns one column quarter: 16 rows = 8 dwords).
__global__ __launch_bounds__(256, 4) void k_transpose(const float* __restrict__ x,
                                                      uint32_t* __restrict__ xt) {
    __shared__ float tile[64][65];
    const int s  = blockIdx.z;
    const int cb = blockIdx.y;                       // 16 col tiles
    const int rb = blockIdx.x;                       // 128 row tiles
    const int tid = threadIdx.x;
    const int tx = tid & 15, ty = tid >> 4;

    const float* src = x + (size_t)(s * NB + rb * 64) * D_FEAT + cb * 64;
#pragma unroll
    for (int i = 0; i < 4; ++i) {
        const int rl = i * 16 + ty;
        const float4 v = *(const float4*)&src[(size_t)rl * D_FEAT + tx * 4];
        tile[rl][tx * 4 + 0] = v.x;
        tile[rl][tx * 4 + 1] = v.y;
        tile[rl][tx * 4 + 2] = v.z;
        tile[rl][tx * 4 + 3] = v.w;
    }
    __syncthreads();
    const int cl = tid >> 2;                         // local column (64)
    const int rq = tid & 3;                          // row quarter (16 rows)
    uint32_t pk[8];
#pragma unroll
    for (int m = 0; m < 8; ++m)
        pk[m] = pkbf2(tile[rq * 16 + 2 * m][cl], tile[rq * 16 + 2 * m + 1][cl]);
    uint32_t* dst = xt + (size_t)(s * D_FEAT + cb * 64 + cl) * 4096 + rb * 32 + rq * 8;
    *(uint4*)&dst[0] = make_uint4(pk[0], pk[1], pk[2], pk[3]);
    *(uint4*)&dst[4] = make_uint4(pk[4], pk[5], pk[6], pk[7]);
}

// ---------------- Pass 1a: per-block partial Sxx and Sx from xT -------------------
// 256 threads; thread = (g = tid>>2, q = tid&3) owns 4 permuted columns; its
// block's 32 rows of one column = 64 contiguous bytes = 4 uint4 loads. DPP
// rebuilds v[16] per row; acc[i][jj] = sum v[i]*vq[jj]. No LDS, no barriers.
__global__ __launch_bounds__(256, 3) void k_stats_gather(const uint32_t* __restrict__ xt,
                                                         const int* __restrict__ perms,
                                                         uint32_t* __restrict__ part) {
    const int s   = blockIdx.y;
    const int p   = blockIdx.x;
    const int tid = threadIdx.x;

    int pcolq[4];
#pragma unroll
    for (int jj = 0; jj < 4; ++jj) pcolq[jj] = perms[s * D_FEAT + tid * 4 + jj];

    float acc[GD][4];
#pragma unroll
    for (int i = 0; i < GD; ++i)
#pragma unroll
        for (int jj = 0; jj < 4; ++jj) acc[i][jj] = 0.0f;
    float sacc[4] = {0.0f, 0.0f, 0.0f, 0.0f};

    const uint4* xt4 = (const uint4*)xt;
    // per-column uint4 base for this block's 32 rows
    const size_t b0 = (size_t)(s * D_FEAT + pcolq[0]) * 1024 + p * 4;
    const size_t b1 = (size_t)(s * D_FEAT + pcolq[1]) * 1024 + p * 4;
    const size_t b2 = (size_t)(s * D_FEAT + pcolq[2]) * 1024 + p * 4;
    const size_t b3 = (size_t)(s * D_FEAT + pcolq[3]) * 1024 + p * 4;

// one row from packed dwords D0..D3 (per-column), LO: low bf16, else high
#define ROW_ACC_P(D0, D1, D2, D3, LO)                                          \
    {                                                                          \
        float vq_[4];                                                          \
        if (LO) {                                                              \
            vq_[0] = __uint_as_float((D0) << 16);                              \
            vq_[1] = __uint_as_float((D1) << 16);                              \
            vq_[2] = __uint_as_float((D2) << 16);                              \
            vq_[3] = __uint_as_float((D3) << 16);                              \
        } else {                                                               \
            vq_[0] = __uint_as_float((D0) & 0xFFFF0000u);                      \
            vq_[1] = __uint_as_float((D1) & 0xFFFF0000u);                      \
            vq_[2] = __uint_as_float((D2) & 0xFFFF0000u);                      \
            vq_[3] = __uint_as_float((D3) & 0xFFFF0000u);                      \
        }                                                                      \
        float v_[GD];                                                          \
        _Pragma("unroll")                                                      \
        for (int jj = 0; jj < 4; ++jj) {                                       \
            v_[0  + jj] = qbc<0>(vq_[jj]);                                     \
            v_[4  + jj] = qbc<1>(vq_[jj]);                                     \
            v_[8  + jj] = qbc<2>(vq_[jj]);                                     \
            v_[12 + jj] = qbc<3>(vq_[jj]);                                     \
        }                                                                      \
        _Pragma("unroll")                                                      \
        for (int jj = 0; jj < 4; ++jj) sacc[jj] += vq_[jj];                    \
        _Pragma("unroll")                                                      \
        for (int i = 0; i < GD; ++i)                                           \
            _Pragma("unroll")                                                  \
            for (int jj = 0; jj < 4; ++jj)                                     \
                acc[i][jj] = fmaf(v_[i], vq_[jj], acc[i][jj]);                 \
    }

#pragma unroll
    for (int seg = 0; seg < 4; ++seg) {              // 8 rows per seg
        const uint4 U0 = xt4[b0 + seg];
        const uint4 U1 = xt4[b1 + seg];
        const uint4 U2 = xt4[b2 + seg];
        const uint4 U3 = xt4[b3 + seg];
        ROW_ACC_P(U0.x, U1.x, U2.x, U3.x, 1) ROW_ACC_P(U0.x, U1.x, U2.x, U3.x, 0)
        ROW_ACC_P(U0.y, U1.y, U2.y, U3.y, 1) ROW_ACC_P(U0.y, U1.y, U2.y, U3.y, 0)
        ROW_ACC_P(U0.z, U1.z, U2.z, U3.z, 1) ROW_ACC_P(U0.z, U1.z, U2.z, U3.z, 0)
        ROW_ACC_P(U0.w, U1.w, U2.w, U3.w, 1) ROW_ACC_P(U0.w, U1.w, U2.w, U3.w, 0)
    }
#undef ROW_ACC_P

    // bf16-packed partial: dword layout [i*512 + tid*2 + h] for Sxx,
    // [8192 + tid*2 + h] for Sx.
    uint32_t* dst = part + (size_t)(s * P1 + p) * PSTRIDE_U32;
#pragma unroll
    for (int i = 0; i < GD; ++i) {
        dst[i * 512 + tid * 2 + 0] = pkbf2(acc[i][0], acc[i][1]);
        dst[i * 512 + tid * 2 + 1] = pkbf2(acc[i][2], acc[i][3]);
    }
    dst[8192 + tid * 2 + 0] = pkbf2(sacc[0], sacc[1]);
    dst[8192 + tid * 2 + 1] = pkbf2(sacc[2], sacc[3]);
}

// ---------------- Pass 1b: reduce bf16 partials, stage 1 (P1 -> PSPLIT) -----------
__global__ __launch_bounds__(256) void k_reduce1(const uint32_t* __restrict__ part,
                                                 float* __restrict__ red) {
    const int fd = blockIdx.x * 256 + threadIdx.x;
    if (fd >= ENT_DW) return;
    const int s = fd / PSTRIDE_U32, ffd = fd % PSTRIDE_U32;
    const uint32_t* src =
        part + ((size_t)s * P1 + blockIdx.y * PER) * PSTRIDE_U32 + ffd;
    float s0 = 0.0f, s1 = 0.0f;
#pragma unroll 8
    for (int p = 0; p < PER; ++p) {
        const uint32_t u = src[(size_t)p * PSTRIDE_U32];
        s0 += __uint_as_float(u << 16);
        s1 += __uint_as_float(u & 0xFFFF0000u);
    }
    float* r = red + (size_t)blockIdx.y * ENT + s * PART_STRIDE + ffd * 2;
    r[0] = s0;
    r[1] = s1;
}

// ---------------- Pass 2: fused final-reduce + W = cov^{-1/2} ----------------
__global__ __launch_bounds__(256) void k_invsqrt(const float* __restrict__ red,
                                                 float* __restrict__ ws) {
    __shared__ float Ym[GD][GD];
    __shared__ float Zm[GD][GD];
    __shared__ float Tm[GD][GD];
    __shared__ float Mu[GD];
    const int bx = blockIdx.x;
    const int s = bx >> 6, g = bx & 63;
    const int tid = threadIdx.x;
    const int i = tid >> 4, j = tid & 15;
    const float invB = 1.0f / (float)NB;

    const int f_sxx = s * PART_STRIDE + i * D_FEAT + g * GD + j;
    float sxx = 0.0f;
#pragma unroll
    for (int pp = 0; pp < PSPLIT; ++pp) sxx += red[(size_t)pp * ENT + f_sxx];

    if (tid < GD) {
        const int f_sx = s * PART_STRIDE + SXX_FLOATS + g * GD + tid;
        float sx = 0.0f;
#pragma unroll
        for (int pp = 0; pp < PSPLIT; ++pp) sx += red[(size_t)pp * ENT + f_sx];
        ws[SX_OFF + s * D_FEAT + g * GD + tid] = sx;
        Mu[tid] = sx * invB;
    }
    __syncthreads();
    const float a = sxx * invB - Mu[i] * Mu[j];   // cov entry

    Ym[i][j] = a;
    __syncthreads();
    float tr = 0.0f;
#pragma unroll
    for (int k = 0; k < GD; ++k) tr += Ym[k][k];
    const float sc = tr * (1.0f / (float)GD);
    const float inv_sc = 1.0f / sc;
    __syncthreads();
    Ym[i][j] = a * inv_sc;
    Zm[i][j] = (i == j) ? 1.0f : 0.0f;
    __syncthreads();

    float zn = (i == j) ? 1.0f : 0.0f;
    for (int it = 0; it < 6; ++it) {
        float t = 0.0f;
#pragma unroll
        for (int k = 0; k < GD; ++k) t += Zm[i][k] * Ym[k][j];
        t = ((i == j) ? 1.5f : 0.0f) - 0.5f * t;
        Tm[i][j] = t;
        __syncthreads();
        float yn = 0.0f;
        zn = 0.0f;
#pragma unroll
        for (int k = 0; k < GD; ++k) {
            yn += Ym[i][k] * Tm[k][j];
            zn += Tm[i][k] * Zm[k][j];
        }
        __syncthreads();
        Ym[i][j] = yn;
        Zm[i][j] = zn;
        __syncthreads();
    }
    ws[W_OFF + (size_t)((s * NGROUP + g) * GD + i) * GD + j] = zn * rsqrtf(sc);
}

// ---------------- Pass 3: y = (x_gathered - mu) @ W, scattered back ----------------
// (Exact R5/R8/R10/R11 kernel — proven.)
__global__ __launch_bounds__(256, 3) void k_apply(const float* __restrict__ x,
                                                  const int* __restrict__ perms,
                                                  const float* __restrict__ ws,
                                                  float* __restrict__ out) {
    __shared__ float bin[2][C3][D_FEAT];
    __shared__ float bout[C3][D_FEAT];
    const int s   = blockIdx.y;
    const int rb  = blockIdx.x;
    const int tid = threadIdx.x;
    const int g   = tid >> 2;
    const int q   = tid & 3;
    const float invB = 1.0f / (float)NB;

    int pcolq[4];
#pragma unroll
    for (int jj = 0; jj < 4; ++jj) pcolq[jj] = perms[s * D_FEAT + tid * 4 + jj];

    const float* Wp = ws + W_OFF + (size_t)(s * NGROUP + g) * GD * GD;
    float w[GD][4];
#pragma unroll
    for (int e = 0; e < GD; ++e) {
        float4 t4 = *(const float4*)&Wp[e * GD + q * 4];
        w[e][0] = t4.x; w[e][1] = t4.y; w[e][2] = t4.z; w[e][3] = t4.w;
    }
    float bias[4] = {0.0f, 0.0f, 0.0f, 0.0f};
#pragma unroll
    for (int e = 0; e < GD; ++e) {
        const float mu = ws[SX_OFF + s * D_FEAT + g * GD + e] * invB;
#pragma unroll
        for (int ii = 0; ii < 4; ++ii) bias[ii] += mu * w[e][ii];
    }

    const float* xbase = x + (size_t)(s * NB + rb * RPB3) * D_FEAT;
    float* obase = out + (size_t)(s * NB + rb * RPB3) * D_FEAT;
    constexpr int NCH = RPB3 / C3;

    float4 rr[C3];
#pragma unroll
    for (int t = 0; t < C3; ++t)
        rr[t] = *(const float4*)&xbase[(size_t)t * D_FEAT + tid * 4];

    for (int k = 0; k < NCH; ++k) {
#pragma unroll
        for (int t = 0; t < C3; ++t)
            *(float4*)&bin[k & 1][t][tid * 4] = rr[t];
        __syncthreads();
        if (k + 1 < NCH) {
            const float* nx = xbase + (size_t)(k + 1) * C3 * D_FEAT;
#pragma unroll
            for (int t = 0; t < C3; ++t)
                rr[t] = *(const float4*)&nx[(size_t)t * D_FEAT + tid * 4];
        }
        const float (*cb)[D_FEAT] = bin[k & 1];
#pragma unroll
        for (int r = 0; r < C3; ++r) {
            float vq[4];
#pragma unroll
            for (int jj = 0; jj < 4; ++jj) vq[jj] = cb[r][pcolq[jj]];
            float v[GD];
#pragma unroll
            for (int jj = 0; jj < 4; ++jj) {
                v[0  + jj] = qbc<0>(vq[jj]);
                v[4  + jj] = qbc<1>(vq[jj]);
                v[8  + jj] = qbc<2>(vq[jj]);
                v[12 + jj] = qbc<3>(vq[jj]);
            }
            float u[4] = {-bias[0], -bias[1], -bias[2], -bias[3]};
#pragma unroll
            for (int e = 0; e < GD; ++e)
#pragma unroll
                for (int ii = 0; ii < 4; ++ii) u[ii] = fmaf(v[e], w[e][ii], u[ii]);
#pragma unroll
            for (int ii = 0; ii < 4; ++ii) bout[r][pcolq[ii]] = u[ii];
        }
        __syncthreads();
        float* ob = obase + (size_t)k * C3 * D_FEAT;
#pragma unroll
        for (int t = 0; t < C3; ++t)
            *(float4*)&ob[(size_t)t * D_FEAT + tid * 4] =
                *(const float4*)&bout[t][tid * 4];
    }
}

extern "C" void kernel_launch(void* const* d_in, const int* in_sizes, int n_in,
                              void* d_out, int out_size, void* d_ws, size_t ws_size,
                              hipStream_t stream) {
    const float* x     = (const float*)d_in[0];
    const int*   perms = (const int*)d_in[1];
    float* out = (float*)d_out;
    float* ws  = (float*)d_ws;

    // d_out doubles as scratch: [partials 26.7 MB][xT bf16 50.3 MB] = 77 MB
    // of its 100.7 MB; k_apply fully overwrites d_out at the end.
    uint32_t* part = (uint32_t*)out;
    uint32_t* xt   = (uint32_t*)out + XT_OFF_DW;

    dim3 gt(NB / 64, D_FEAT / 64, NVIEW);            // (128, 16, 3)
    k_transpose<<<gt, 256, 0, stream>>>(x, xt);

    dim3 g1(P1, NVIEW);                              // 768 blocks = 3/CU
    k_stats_gather<<<g1, 256, 0, stream>>>(xt, perms, part);

    dim3 gr1((ENT_DW + 255) / 256, PSPLIT);          // (102, 8)
    k_reduce1<<<gr1, 256, 0, stream>>>(part, ws + RED_OFF);

    k_invsqrt<<<NVIEW * NGROUP, 256, 0, stream>>>(ws + RED_OFF, ws);

    dim3 g3(NB / RPB3, NVIEW);                       // 768 blocks = 3/CU
    k_apply<<<g3, 256, 0, stream>>>(x, perms, ws, out);
}

// Round 13
// 96.694 us; speedup vs baseline: 1.2905x; 1.2905x over previous
//
#include <hip/hip_runtime.h>
#include <stdint.h>

// ShuffledGroupWhitening on MI355X.
// x: [3*8192, 1024] f32, perms: [3,1024] i32.
// Per (view s, group g): gather 16 permuted cols, center over batch,
// whiten with cov^{-1/2} (Newton-Schulz), scatter back (same col set).
//
// R12 -> R13: REVERT to R11 (best: 96.8 us). R12's transpose+stats pair cost
// ~87 us vs R11's 58 us stats -- the extra 150 MB transpose pass isn't repaid
// by the cheaper contiguous gather (TA still serializes 64 scattered lane
// addresses per instruction). Stats wall (~58 us) now replicated across five
// structures (LDS-staged, LDS-pipelined, direct-gather, 2xTLP, transposed):
// treating it as the scattered-touch floor. Composition at component floors:
// apply ~29 us = 200 MB stream; reduce+invsqrt ~9 us tail.

constexpr int D_FEAT  = 1024;
constexpr int NGROUP  = 64;
constexpr int GD      = 16;     // group dim
constexpr int NB      = 8192;   // rows per view
constexpr int NVIEW   = 3;

constexpr int P1      = 256;    // stats blocks per view (768 total = 3/CU)
constexpr int RPP1    = NB / P1;        // 32 rows per stats block
constexpr int RPB3    = 32;     // rows per apply block
constexpr int C3      = 4;      // chunk rows (apply)
constexpr int PSPLIT  = 8;      // reduce split factor
constexpr int PER     = P1 / PSPLIT;    // 32 partials per reduce1 block

constexpr int SXX_FLOATS  = NGROUP * GD * GD;        // 16384 per view
constexpr int PART_STRIDE = SXX_FLOATS + D_FEAT;     // 17408 entries per partial
constexpr int PSTRIDE_U32 = PART_STRIDE / 2;         // 8704 dwords (bf16-packed)
constexpr int ENT         = NVIEW * PART_STRIDE;     // 52224 stat entries
constexpr int ENT_DW      = NVIEW * PSTRIDE_U32;     // 26112 packed dwords

// ws layout (floats) — partials live in d_out, NOT here
constexpr int SX_OFF  = 0;                           // [3][1024] raw col sums
constexpr int W_OFF   = SX_OFF + NVIEW * D_FEAT;     // 3072: [3][64][16][16]
constexpr int RED_OFF = W_OFF + NVIEW * SXX_FLOATS;  // 52224: [8][52224] f32
// total ws use = RED_OFF + PSPLIT*ENT = 470016 floats ~ 1.9 MB

// quad broadcast: every lane gets lane ((lane&~3)+B)'s value. Pure VALU DPP.
template <int B>
__device__ __forceinline__ float qbc(float x) {
    return __int_as_float(__builtin_amdgcn_mov_dpp(
        __float_as_int(x), B * 0x55 /*quad_perm[B,B,B,B]*/, 0xF, 0xF, true));
}

// pack two floats to bf16x2 (round-to-nearest-even), a in low half
__device__ __forceinline__ uint32_t pkbf2(float a, float b) {
    uint32_t ua = __float_as_uint(a), ub = __float_as_uint(b);
    ua += 0x7FFFu + ((ua >> 16) & 1u);
    ub += 0x7FFFu + ((ub >> 16) & 1u);
    return (ua >> 16) | (ub & 0xFFFF0000u);
}

// ---------------- Pass 1a: per-block partial Sxx and Sx (bf16-packed) -------------
// 256 threads; thread = (g = tid>>2, q = tid&3) gathers its own quad directly
// from global (block reads whole rows -> L2/L3 absorb line overlap), DPP
// rebuilds v[16], accumulates acc[i][jj] = sum v[i]*vq[jj]. R8 hot loop.
__global__ __launch_bounds__(256, 3) void k_stats_gather(const float* __restrict__ x,
                                                         const int* __restrict__ perms,
                                                         uint32_t* __restrict__ part) {
    const int s   = blockIdx.y;
    const int p   = blockIdx.x;
    const int tid = threadIdx.x;

    // this thread's 4 permuted column indices (coalesced load)
    int pcolq[4];
#pragma unroll
    for (int jj = 0; jj < 4; ++jj) pcolq[jj] = perms[s * D_FEAT + tid * 4 + jj];

    float acc[GD][4];
#pragma unroll
    for (int i = 0; i < GD; ++i)
#pragma unroll
        for (int jj = 0; jj < 4; ++jj) acc[i][jj] = 0.0f;
    float sacc[4] = {0.0f, 0.0f, 0.0f, 0.0f};

    const float* xbase = x + (size_t)(s * NB + p * RPP1) * D_FEAT;

// accumulate one row given its 4 gathered quad values
#define ROW_ACC(Q0, Q1, Q2, Q3)                                                \
    {                                                                          \
        float vq_[4] = {Q0, Q1, Q2, Q3};                                       \
        float v_[GD];                                                          \
        _Pragma("unroll")                                                      \
        for (int jj = 0; jj < 4; ++jj) {                                       \
            v_[0  + jj] = qbc<0>(vq_[jj]);                                     \
            v_[4  + jj] = qbc<1>(vq_[jj]);                                     \
            v_[8  + jj] = qbc<2>(vq_[jj]);                                     \
            v_[12 + jj] = qbc<3>(vq_[jj]);                                     \
        }                                                                      \
        _Pragma("unroll")                                                      \
        for (int jj = 0; jj < 4; ++jj) sacc[jj] += vq_[jj];                    \
        _Pragma("unroll")                                                      \
        for (int i = 0; i < GD; ++i)                                           \
            _Pragma("unroll")                                                  \
            for (int jj = 0; jj < 4; ++jj)                                     \
                acc[i][jj] = fmaf(v_[i], vq_[jj], acc[i][jj]);                 \
    }

    // 4 rows per iteration: 16 independent dword gathers in flight per wave.
    for (int r = 0; r < RPP1; r += 4) {
        const float* r0 = xbase + (size_t)r * D_FEAT;
        const float* r1 = r0 + D_FEAT;
        const float* r2 = r1 + D_FEAT;
        const float* r3 = r2 + D_FEAT;
        const float a0 = r0[pcolq[0]], a1 = r0[pcolq[1]],
                    a2 = r0[pcolq[2]], a3 = r0[pcolq[3]];
        const float b0 = r1[pcolq[0]], b1 = r1[pcolq[1]],
                    b2 = r1[pcolq[2]], b3 = r1[pcolq[3]];
        const float c0 = r2[pcolq[0]], c1 = r2[pcolq[1]],
                    c2 = r2[pcolq[2]], c3 = r2[pcolq[3]];
        const float d0 = r3[pcolq[0]], d1 = r3[pcolq[1]],
                    d2 = r3[pcolq[2]], d3 = r3[pcolq[3]];
        ROW_ACC(a0, a1, a2, a3)
        ROW_ACC(b0, b1, b2, b3)
        ROW_ACC(c0, c1, c2, c3)
        ROW_ACC(d0, d1, d2, d3)
    }
#undef ROW_ACC

    // bf16-packed partial: dword layout [i*512 + tid*2 + h] for Sxx,
    // [8192 + tid*2 + h] for Sx; entry (i*1024 + tid*4 + jj) <-> dword
    // (i*512 + tid*2 + (jj>>1)), half jj&1.
    uint32_t* dst = part + (size_t)(s * P1 + p) * PSTRIDE_U32;
#pragma unroll
    for (int i = 0; i < GD; ++i) {
        dst[i * 512 + tid * 2 + 0] = pkbf2(acc[i][0], acc[i][1]);
        dst[i * 512 + tid * 2 + 1] = pkbf2(acc[i][2], acc[i][3]);
    }
    dst[8192 + tid * 2 + 0] = pkbf2(sacc[0], sacc[1]);
    dst[8192 + tid * 2 + 1] = pkbf2(sacc[2], sacc[3]);
}

// ---------------- Pass 1b: reduce bf16 partials, stage 1 (P1 -> PSPLIT) -----------
// one thread per packed dword (2 entries); coalesced reads per p-iter.
// red[pp][f] holds f32 sums at natural entry index f (i*1024 + c' for Sxx,
// 16384 + c' for Sx), per view offset s*PART_STRIDE.
__global__ __launch_bounds__(256) void k_reduce1(const uint32_t* __restrict__ part,
                                                 float* __restrict__ red) {
    const int fd = blockIdx.x * 256 + threadIdx.x;
    if (fd >= ENT_DW) return;
    const int s = fd / PSTRIDE_U32, ffd = fd % PSTRIDE_U32;
    const uint32_t* src =
        part + ((size_t)s * P1 + blockIdx.y * PER) * PSTRIDE_U32 + ffd;
    float s0 = 0.0f, s1 = 0.0f;
#pragma unroll 8
    for (int p = 0; p < PER; ++p) {
        const uint32_t u = src[(size_t)p * PSTRIDE_U32];
        s0 += __uint_as_float(u << 16);
        s1 += __uint_as_float(u & 0xFFFF0000u);
    }
    float* r = red + (size_t)blockIdx.y * ENT + s * PART_STRIDE + ffd * 2;
    r[0] = s0;
    r[1] = s1;
}

// ---------------- Pass 2: fused final-reduce + W = cov^{-1/2} ----------------
// one block per (s,g); thread (i = tid>>4, j = tid&15) sums its Sxx entry over
// the 8 red slices, threads 0..15 produce mu and store raw Sx to ws for apply,
// then Newton-Schulz in LDS.
__global__ __launch_bounds__(256) void k_invsqrt(const float* __restrict__ red,
                                                 float* __restrict__ ws) {
    __shared__ float Ym[GD][GD];
    __shared__ float Zm[GD][GD];
    __shared__ float Tm[GD][GD];
    __shared__ float Mu[GD];
    const int bx = blockIdx.x;
    const int s = bx >> 6, g = bx & 63;
    const int tid = threadIdx.x;
    const int i = tid >> 4, j = tid & 15;
    const float invB = 1.0f / (float)NB;

    // final 8-way reduction for this thread's Sxx entry
    const int f_sxx = s * PART_STRIDE + i * D_FEAT + g * GD + j;
    float sxx = 0.0f;
#pragma unroll
    for (int pp = 0; pp < PSPLIT; ++pp) sxx += red[(size_t)pp * ENT + f_sxx];

    // threads 0..15: final Sx sum -> mu (LDS) + raw Sx to ws (apply reads it)
    if (tid < GD) {
        const int f_sx = s * PART_STRIDE + SXX_FLOATS + g * GD + tid;
        float sx = 0.0f;
#pragma unroll
        for (int pp = 0; pp < PSPLIT; ++pp) sx += red[(size_t)pp * ENT + f_sx];
        ws[SX_OFF + s * D_FEAT + g * GD + tid] = sx;
        Mu[tid] = sx * invB;
    }
    __syncthreads();
    const float a = sxx * invB - Mu[i] * Mu[j];   // cov entry

    Ym[i][j] = a;
    __syncthreads();
    float tr = 0.0f;
#pragma unroll
    for (int k = 0; k < GD; ++k) tr += Ym[k][k];
    const float sc = tr * (1.0f / (float)GD);   // ~1.0 for N(0,1) data
    const float inv_sc = 1.0f / sc;
    __syncthreads();                            // all trace reads done
    Ym[i][j] = a * inv_sc;                      // normalized A, eig in ~[0.9,1.1]
    Zm[i][j] = (i == j) ? 1.0f : 0.0f;
    __syncthreads();

    float zn = (i == j) ? 1.0f : 0.0f;
    for (int it = 0; it < 6; ++it) {
        float t = 0.0f;
#pragma unroll
        for (int k = 0; k < GD; ++k) t += Zm[i][k] * Ym[k][j];
        t = ((i == j) ? 1.5f : 0.0f) - 0.5f * t;
        Tm[i][j] = t;
        __syncthreads();
        float yn = 0.0f;
        zn = 0.0f;
#pragma unroll
        for (int k = 0; k < GD; ++k) {
            yn += Ym[i][k] * Tm[k][j];
            zn += Tm[i][k] * Zm[k][j];
        }
        __syncthreads();
        Ym[i][j] = yn;
        Zm[i][j] = zn;
        __syncthreads();
    }
    // W = Z * sc^{-1/2}
    ws[W_OFF + (size_t)((s * NGROUP + g) * GD + i) * GD + j] = zn * rsqrtf(sc);
}

// ---------------- Pass 3: y = (x_gathered - mu) @ W, scattered back ----------------
// block: 256 threads; thread = (g = tid>>2, q = tid&3) owns W[:, q*4..q*4+3] in regs;
// gathers its quad from LDS, rebuilds v[16] via DPP, scatters u[4] to bout.
// (Exact R5/R8/R10/R11 kernel — proven.)
__global__ __launch_bounds__(256, 3) void k_apply(const float* __restrict__ x,
                                                  const int* __restrict__ perms,
                                                  const float* __restrict__ ws,
                                                  float* __restrict__ out) {
    __shared__ float bin[2][C3][D_FEAT];             // 32 KB double-buffered input
    __shared__ float bout[C3][D_FEAT];               // 16 KB output staging
    const int s   = blockIdx.y;
    const int rb  = blockIdx.x;
    const int tid = threadIdx.x;
    const int g   = tid >> 2;
    const int q   = tid & 3;
    const float invB = 1.0f / (float)NB;

    int pcolq[4];
#pragma unroll
    for (int jj = 0; jj < 4; ++jj) pcolq[jj] = perms[s * D_FEAT + tid * 4 + jj];

    // W columns for this thread: w[e][ii] = W[s,g][e][q*4+ii]
    const float* Wp = ws + W_OFF + (size_t)(s * NGROUP + g) * GD * GD;
    float w[GD][4];
#pragma unroll
    for (int e = 0; e < GD; ++e) {
        float4 t4 = *(const float4*)&Wp[e * GD + q * 4];
        w[e][0] = t4.x; w[e][1] = t4.y; w[e][2] = t4.z; w[e][3] = t4.w;
    }
    // bias[ii] = sum_e mu[e] * w[e][ii]  (fold centering into the GEMV)
    float bias[4] = {0.0f, 0.0f, 0.0f, 0.0f};
#pragma unroll
    for (int e = 0; e < GD; ++e) {
        const float mu = ws[SX_OFF + s * D_FEAT + g * GD + e] * invB;
#pragma unroll
        for (int ii = 0; ii < 4; ++ii) bias[ii] += mu * w[e][ii];
    }

    const float* xbase = x + (size_t)(s * NB + rb * RPB3) * D_FEAT;
    float* obase = out + (size_t)(s * NB + rb * RPB3) * D_FEAT;
    constexpr int NCH = RPB3 / C3;                   // 8 chunks

    float4 rr[C3];
#pragma unroll
    for (int t = 0; t < C3; ++t)
        rr[t] = *(const float4*)&xbase[(size_t)t * D_FEAT + tid * 4];

    for (int k = 0; k < NCH; ++k) {
#pragma unroll
        for (int t = 0; t < C3; ++t)
            *(float4*)&bin[k & 1][t][tid * 4] = rr[t];
        __syncthreads();                             // bin[k&1] visible; bout(k-1) stores done
        if (k + 1 < NCH) {                           // prefetch under compute
            const float* nx = xbase + (size_t)(k + 1) * C3 * D_FEAT;
#pragma unroll
            for (int t = 0; t < C3; ++t)
                rr[t] = *(const float4*)&nx[(size_t)t * D_FEAT + tid * 4];
        }
        const float (*cb)[D_FEAT] = bin[k & 1];
#pragma unroll
        for (int r = 0; r < C3; ++r) {
            float vq[4];
#pragma unroll
            for (int jj = 0; jj < 4; ++jj) vq[jj] = cb[r][pcolq[jj]];
            float v[GD];
#pragma unroll
            for (int jj = 0; jj < 4; ++jj) {
                v[0  + jj] = qbc<0>(vq[jj]);
                v[4  + jj] = qbc<1>(vq[jj]);
                v[8  + jj] = qbc<2>(vq[jj]);
                v[12 + jj] = qbc<3>(vq[jj]);
            }
            float u[4] = {-bias[0], -bias[1], -bias[2], -bias[3]};
#pragma unroll
            for (int e = 0; e < GD; ++e)
#pragma unroll
                for (int ii = 0; ii < 4; ++ii) u[ii] = fmaf(v[e], w[e][ii], u[ii]);
#pragma unroll
            for (int ii = 0; ii < 4; ++ii) bout[r][pcolq[ii]] = u[ii];
        }
        __syncthreads();                             // bout complete
        float* ob = obase + (size_t)k * C3 * D_FEAT;
#pragma unroll
        for (int t = 0; t < C3; ++t)
            *(float4*)&ob[(size_t)t * D_FEAT + tid * 4] =
                *(const float4*)&bout[t][tid * 4];
    }
}

extern "C" void kernel_launch(void* const* d_in, const int* in_sizes, int n_in,
                              void* d_out, int out_size, void* d_ws, size_t ws_size,
                              hipStream_t stream) {
    const float* x     = (const float*)d_in[0];
    const int*   perms = (const int*)d_in[1];
    float* out = (float*)d_out;
    float* ws  = (float*)d_ws;

    // bf16-packed partials (768 * 8704 dwords = 26.7 MB) live in d_out:
    // it is 100.7 MB and k_apply fully overwrites every element afterwards.
    uint32_t* part = (uint32_t*)out;

    dim3 g1(P1, NVIEW);                              // 768 blocks = 3/CU
    k_stats_gather<<<g1, 256, 0, stream>>>(x, perms, part);

    dim3 gr1((ENT_DW + 255) / 256, PSPLIT);          // (102, 8)
    k_reduce1<<<gr1, 256, 0, stream>>>(part, ws + RED_OFF);

    k_invsqrt<<<NVIEW * NGROUP, 256, 0, stream>>>(ws + RED_OFF, ws);

    dim3 g3(NB / RPB3, NVIEW);                       // 768 blocks = 3/CU
    k_apply<<<g3, 256, 0, stream>>>(x, perms, ws, out);
}